// Round 1
// baseline (174.511 us; speedup 1.0000x reference)
//
#include <hip/hip_runtime.h>
#include <hip/hip_bf16.h>
#include <cstddef>

// Problem constants (from reference): N=100000, E=1600000
constexpr int HID  = 128;   // hidden dim
constexpr int OUTW = 32;    // N_CHUNKS * STRU = 8*4
constexpr int STRU = 4;
constexpr int NCH  = 8;

__device__ __forceinline__ float dot4(float4 a, float4 b) {
    return a.x * b.x + a.y * b.y + a.z * b.z + a.w * b.w;
}

// ---------------------------------------------------------------------------
// Kernel 1: per-node projections  P[n][32] = x[n]@Wq.T + bq,  Q likewise.
// One thread per node. Weight reads are wave-uniform -> scalar loads.
// ---------------------------------------------------------------------------
__global__ __launch_bounds__(256) void proj_kernel(
    const float* __restrict__ x,
    const float* __restrict__ Wq, const float* __restrict__ bq,
    const float* __restrict__ Wv, const float* __restrict__ bv,
    float* __restrict__ P, float* __restrict__ Q, int n_nodes)
{
    int n = blockIdx.x * blockDim.x + threadIdx.x;
    if (n >= n_nodes) return;

    const float4* __restrict__ x4  = reinterpret_cast<const float4*>(x + (size_t)n * HID);
    const float4* __restrict__ Wq4 = reinterpret_cast<const float4*>(Wq);
    const float4* __restrict__ Wv4 = reinterpret_cast<const float4*>(Wv);

    float accP[OUTW];
    float accQ[OUTW];
#pragma unroll
    for (int o = 0; o < OUTW; ++o) { accP[o] = bq[o]; accQ[o] = bv[o]; }

    for (int kc = 0; kc < HID / 4; ++kc) {
        float4 xv = x4[kc];
#pragma unroll
        for (int o = 0; o < OUTW; ++o) {
            accP[o] += dot4(xv, Wq4[o * (HID / 4) + kc]);
            accQ[o] += dot4(xv, Wv4[o * (HID / 4) + kc]);
        }
    }

    float4* __restrict__ P4 = reinterpret_cast<float4*>(P + (size_t)n * OUTW);
    float4* __restrict__ Q4 = reinterpret_cast<float4*>(Q + (size_t)n * OUTW);
#pragma unroll
    for (int c = 0; c < OUTW / 4; ++c) {
        P4[c] = make_float4(accP[4*c+0], accP[4*c+1], accP[4*c+2], accP[4*c+3]);
        Q4[c] = make_float4(accQ[4*c+0], accQ[4*c+1], accQ[4*c+2], accQ[4*c+3]);
    }
}

// ---------------------------------------------------------------------------
// Kernel 2: per-edge gather + multiply + chunk-sum + sigmoid.
// out[s*E + i] = sigmoid(sum_c P[e0][s*8+c]*Q[e1][s*8+c]) * scale + 1
// ---------------------------------------------------------------------------
__global__ __launch_bounds__(256) void edge_kernel(
    const int* __restrict__ e,
    const float* __restrict__ P, const float* __restrict__ Q,
    const float* __restrict__ ratio_p,
    float* __restrict__ out, int E_)
{
    int i = blockIdx.x * blockDim.x + threadIdx.x;
    if (i >= E_) return;

    float scale = (1.0f - ratio_p[0]) * 0.5f;

    int e0 = e[i];
    int e1 = e[E_ + i];

    const float4* __restrict__ p4 = reinterpret_cast<const float4*>(P + (size_t)e0 * OUTW);
    const float4* __restrict__ q4 = reinterpret_cast<const float4*>(Q + (size_t)e1 * OUTW);

#pragma unroll
    for (int s = 0; s < STRU; ++s) {
        float4 a0 = p4[s * 2 + 0];
        float4 a1 = p4[s * 2 + 1];
        float4 b0 = q4[s * 2 + 0];
        float4 b1 = q4[s * 2 + 1];
        float sum = dot4(a0, b0) + dot4(a1, b1);
        float sig = 1.0f / (1.0f + __expf(-sum));
        out[(size_t)s * E_ + i] = sig * scale + 1.0f;
    }
}

// ---------------------------------------------------------------------------
// Fallback: fully fused per-edge (used only if workspace is too small).
// ---------------------------------------------------------------------------
__global__ __launch_bounds__(256) void fused_kernel(
    const float* __restrict__ x,
    const int* __restrict__ e,
    const float* __restrict__ ratio_p,
    const float* __restrict__ Wq, const float* __restrict__ bq,
    const float* __restrict__ Wv, const float* __restrict__ bv,
    float* __restrict__ out, int E_)
{
    int i = blockIdx.x * blockDim.x + threadIdx.x;
    if (i >= E_) return;

    float scale = (1.0f - ratio_p[0]) * 0.5f;
    int e0 = e[i];
    int e1 = e[E_ + i];

    const float4* __restrict__ xu  = reinterpret_cast<const float4*>(x + (size_t)e0 * HID);
    const float4* __restrict__ xv_ = reinterpret_cast<const float4*>(x + (size_t)e1 * HID);
    const float4* __restrict__ Wq4 = reinterpret_cast<const float4*>(Wq);
    const float4* __restrict__ Wv4 = reinterpret_cast<const float4*>(Wv);

    float accP[OUTW];
    float accQ[OUTW];
#pragma unroll
    for (int o = 0; o < OUTW; ++o) { accP[o] = bq[o]; accQ[o] = bv[o]; }

    for (int kc = 0; kc < HID / 4; ++kc) {
        float4 u = xu[kc];
        float4 v = xv_[kc];
#pragma unroll
        for (int o = 0; o < OUTW; ++o) {
            accP[o] += dot4(u, Wq4[o * (HID / 4) + kc]);
            accQ[o] += dot4(v, Wv4[o * (HID / 4) + kc]);
        }
    }

#pragma unroll
    for (int s = 0; s < STRU; ++s) {
        float sum = 0.0f;
#pragma unroll
        for (int c = 0; c < NCH; ++c) sum += accP[s * NCH + c] * accQ[s * NCH + c];
        float sig = 1.0f / (1.0f + __expf(-sum));
        out[(size_t)s * E_ + i] = sig * scale + 1.0f;
    }
}

extern "C" void kernel_launch(void* const* d_in, const int* in_sizes, int n_in,
                              void* d_out, int out_size, void* d_ws, size_t ws_size,
                              hipStream_t stream)
{
    const float* x     = (const float*)d_in[0];
    const int*   e     = (const int*)  d_in[1];
    const float* ratio = (const float*)d_in[2];
    const float* Wq    = (const float*)d_in[3];
    const float* bq    = (const float*)d_in[4];
    const float* Wv    = (const float*)d_in[5];
    const float* bv    = (const float*)d_in[6];
    float* out = (float*)d_out;

    int N_ = in_sizes[0] / HID;
    int E_ = in_sizes[1] / 2;

    size_t need = (size_t)2 * N_ * OUTW * sizeof(float);
    if (ws_size >= need) {
        float* P = (float*)d_ws;
        float* Q = P + (size_t)N_ * OUTW;
        proj_kernel<<<(N_ + 255) / 256, 256, 0, stream>>>(x, Wq, bq, Wv, bv, P, Q, N_);
        edge_kernel<<<(E_ + 255) / 256, 256, 0, stream>>>(e, P, Q, ratio, out, E_);
    } else {
        fused_kernel<<<(E_ + 255) / 256, 256, 0, stream>>>(x, e, ratio, Wq, bq, Wv, bv, out, E_);
    }
}

// Round 2
// 150.614 us; speedup vs baseline: 1.1587x; 1.1587x over previous
//
#include <hip/hip_runtime.h>
#include <hip/hip_bf16.h>
#include <cstddef>

// Problem constants: N=100000, E=1600000
constexpr int HID  = 128;   // hidden dim
constexpr int OUTW = 32;    // N_CHUNKS * STRU
constexpr int TOT  = 64;    // P outs + Q outs
constexpr int STRU = 4;
constexpr int NCH  = 8;
constexpr int BK   = 16;    // K-chunk staged in LDS
constexpr int ROWS = 256;   // nodes per block

__device__ __forceinline__ float dot4(float4 a, float4 b) {
    return a.x * b.x + a.y * b.y + a.z * b.z + a.w * b.w;
}

// ---------------------------------------------------------------------------
// Prep: WT[k][o] (k<128, o<64): o<32 -> Wq[o][k], o>=32 -> Wv[o-32][k].
// bias[o] likewise. 32 KB + 256 B, runs in ~µs.
// ---------------------------------------------------------------------------
__global__ __launch_bounds__(256) void prep_kernel(
    const float* __restrict__ Wq, const float* __restrict__ bq,
    const float* __restrict__ Wv, const float* __restrict__ bv,
    float* __restrict__ WT, float* __restrict__ bias)
{
    int tid = blockIdx.x * blockDim.x + threadIdx.x;
    for (int idx = tid; idx < HID * TOT; idx += gridDim.x * blockDim.x) {
        int k = idx >> 6, o = idx & 63;
        WT[idx] = (o < OUTW) ? Wq[o * HID + k] : Wv[(o - OUTW) * HID + k];
    }
    if (tid < TOT) bias[tid] = (tid < OUTW) ? bq[tid] : bv[tid - OUTW];
}

// ---------------------------------------------------------------------------
// Proj v2: lane = node, 64 accumulators in VGPRs, weights via wave-uniform
// s_loads from WT, x staged in LDS (pad +1, conflict-free reads).
// ---------------------------------------------------------------------------
__global__ __launch_bounds__(256) void proj2_kernel(
    const float* __restrict__ x, const float* __restrict__ WT,
    const float* __restrict__ bias,
    float* __restrict__ P, float* __restrict__ Q, int n_nodes)
{
    __shared__ float xs[ROWS][BK + 1];
    const int tid  = threadIdx.x;
    const int base = blockIdx.x * ROWS;
    const int node = base + tid;

    float acc[TOT];
#pragma unroll
    for (int o = 0; o < TOT; ++o) acc[o] = bias[o];   // uniform -> s_load

    // cooperative-load geometry: ROWS*BK floats / (256 thr * 4) = 4 float4/thr
    const int lc  = (tid & 3) * 4;   // col within chunk (0,4,8,12)
    const int lr0 = tid >> 2;        // row base (0..63)

#pragma unroll 1
    for (int kc = 0; kc < HID / BK; ++kc) {
        if (kc) __syncthreads();
#pragma unroll
        for (int j = 0; j < 4; ++j) {
            int r  = lr0 + 64 * j;
            int gn = base + r;
            float4 v = make_float4(0.f, 0.f, 0.f, 0.f);
            if (gn < n_nodes)
                v = *reinterpret_cast<const float4*>(x + (size_t)gn * HID + kc * BK + lc);
            xs[r][lc + 0] = v.x; xs[r][lc + 1] = v.y;
            xs[r][lc + 2] = v.z; xs[r][lc + 3] = v.w;
        }
        __syncthreads();

        const float* __restrict__ wr = WT + kc * BK * TOT;  // uniform base
#pragma unroll
        for (int k = 0; k < BK; ++k) {
            float a = xs[tid][k];
#pragma unroll
            for (int o = 0; o < TOT; ++o)
                acc[o] = fmaf(a, wr[k * TOT + o], acc[o]);  // v_fmac v, s, v
        }
    }

    if (node < n_nodes) {
        float4* P4 = reinterpret_cast<float4*>(P + (size_t)node * OUTW);
        float4* Q4 = reinterpret_cast<float4*>(Q + (size_t)node * OUTW);
#pragma unroll
        for (int c = 0; c < OUTW / 4; ++c) {
            P4[c] = make_float4(acc[4*c+0], acc[4*c+1], acc[4*c+2], acc[4*c+3]);
            Q4[c] = make_float4(acc[OUTW+4*c+0], acc[OUTW+4*c+1],
                                acc[OUTW+4*c+2], acc[OUTW+4*c+3]);
        }
    }
}

// ---------------------------------------------------------------------------
// Edge: gather P[e0], Q[e1], chunk-dot, sigmoid. (unchanged this round)
// ---------------------------------------------------------------------------
__global__ __launch_bounds__(256) void edge_kernel(
    const int* __restrict__ e,
    const float* __restrict__ P, const float* __restrict__ Q,
    const float* __restrict__ ratio_p,
    float* __restrict__ out, int E_)
{
    int i = blockIdx.x * blockDim.x + threadIdx.x;
    if (i >= E_) return;

    float scale = (1.0f - ratio_p[0]) * 0.5f;

    int e0 = e[i];
    int e1 = e[E_ + i];

    const float4* __restrict__ p4 = reinterpret_cast<const float4*>(P + (size_t)e0 * OUTW);
    const float4* __restrict__ q4 = reinterpret_cast<const float4*>(Q + (size_t)e1 * OUTW);

#pragma unroll
    for (int s = 0; s < STRU; ++s) {
        float4 a0 = p4[s * 2 + 0];
        float4 a1 = p4[s * 2 + 1];
        float4 b0 = q4[s * 2 + 0];
        float4 b1 = q4[s * 2 + 1];
        float sum = dot4(a0, b0) + dot4(a1, b1);
        float sig = 1.0f / (1.0f + __expf(-sum));
        out[(size_t)s * E_ + i] = sig * scale + 1.0f;
    }
}

// ---------------------------------------------------------------------------
// Fallback: fully fused per-edge (only if workspace too small).
// ---------------------------------------------------------------------------
__global__ __launch_bounds__(256) void fused_kernel(
    const float* __restrict__ x,
    const int* __restrict__ e,
    const float* __restrict__ ratio_p,
    const float* __restrict__ Wq, const float* __restrict__ bq,
    const float* __restrict__ Wv, const float* __restrict__ bv,
    float* __restrict__ out, int E_)
{
    int i = blockIdx.x * blockDim.x + threadIdx.x;
    if (i >= E_) return;

    float scale = (1.0f - ratio_p[0]) * 0.5f;
    int e0 = e[i];
    int e1 = e[E_ + i];

    const float4* __restrict__ xu  = reinterpret_cast<const float4*>(x + (size_t)e0 * HID);
    const float4* __restrict__ xv_ = reinterpret_cast<const float4*>(x + (size_t)e1 * HID);
    const float4* __restrict__ Wq4 = reinterpret_cast<const float4*>(Wq);
    const float4* __restrict__ Wv4 = reinterpret_cast<const float4*>(Wv);

    float s_acc[STRU];
#pragma unroll
    for (int s = 0; s < STRU; ++s) s_acc[s] = 0.0f;

    // process outputs in groups of 8 (one chunk) to bound register use
#pragma unroll 1
    for (int s = 0; s < STRU; ++s) {
        float accP[NCH], accQ[NCH];
#pragma unroll
        for (int c = 0; c < NCH; ++c) { accP[c] = bq[s*NCH+c]; accQ[c] = bv[s*NCH+c]; }
        for (int kc = 0; kc < HID / 4; ++kc) {
            float4 u = xu[kc];
            float4 v = xv_[kc];
#pragma unroll
            for (int c = 0; c < NCH; ++c) {
                int o = s * NCH + c;
                accP[c] += dot4(u, Wq4[o * (HID / 4) + kc]);
                accQ[c] += dot4(v, Wv4[o * (HID / 4) + kc]);
            }
        }
        float sum = 0.0f;
#pragma unroll
        for (int c = 0; c < NCH; ++c) sum += accP[c] * accQ[c];
        s_acc[s] = sum;
    }

#pragma unroll
    for (int s = 0; s < STRU; ++s) {
        float sig = 1.0f / (1.0f + __expf(-s_acc[s]));
        out[(size_t)s * E_ + i] = sig * scale + 1.0f;
    }
}

extern "C" void kernel_launch(void* const* d_in, const int* in_sizes, int n_in,
                              void* d_out, int out_size, void* d_ws, size_t ws_size,
                              hipStream_t stream)
{
    const float* x     = (const float*)d_in[0];
    const int*   e     = (const int*)  d_in[1];
    const float* ratio = (const float*)d_in[2];
    const float* Wq    = (const float*)d_in[3];
    const float* bq    = (const float*)d_in[4];
    const float* Wv    = (const float*)d_in[5];
    const float* bv    = (const float*)d_in[6];
    float* out = (float*)d_out;

    int N_ = in_sizes[0] / HID;
    int E_ = in_sizes[1] / 2;

    size_t needPQ = (size_t)2 * N_ * OUTW * sizeof(float);
    size_t needW  = (size_t)HID * TOT * sizeof(float) + TOT * sizeof(float);
    if (ws_size >= needPQ + needW) {
        float* P    = (float*)d_ws;
        float* Q    = P + (size_t)N_ * OUTW;
        float* WT   = Q + (size_t)N_ * OUTW;
        float* bias = WT + (size_t)HID * TOT;
        prep_kernel<<<32, 256, 0, stream>>>(Wq, bq, Wv, bv, WT, bias);
        proj2_kernel<<<(N_ + ROWS - 1) / ROWS, 256, 0, stream>>>(x, WT, bias, P, Q, N_);
        edge_kernel<<<(E_ + 255) / 256, 256, 0, stream>>>(e, P, Q, ratio, out, E_);
    } else {
        fused_kernel<<<(E_ + 255) / 256, 256, 0, stream>>>(x, e, ratio, Wq, bq, Wv, bv, out, E_);
    }
}

// Round 3
// 77.843 us; speedup vs baseline: 2.2418x; 1.9348x over previous
//
#include <hip/hip_runtime.h>
#include <hip/hip_bf16.h>
#include <cstddef>

// Problem constants: N=100000, E=1600000
constexpr int HID  = 128;
constexpr int OUTW = 32;    // N_CHUNKS * STRU
constexpr int TOT  = 64;    // P outs + Q outs
constexpr int STRU = 4;
constexpr int NCH  = 8;

typedef short  bf16x8 __attribute__((ext_vector_type(8)));
typedef float  f32x4  __attribute__((ext_vector_type(4)));
typedef int    int4v  __attribute__((ext_vector_type(4)));

__device__ __forceinline__ unsigned short f2bf(float f) {
    unsigned u = __builtin_bit_cast(unsigned, f);
    u += 0x7FFFu + ((u >> 16) & 1u);          // round-to-nearest-even
    return (unsigned short)(u >> 16);
}

__device__ __forceinline__ float dot4(float4 a, float4 b) {
    return a.x * b.x + a.y * b.y + a.z * b.z + a.w * b.w;
}

// ---------------------------------------------------------------------------
// Prep: Wb[o][k] bf16 (o<32: Wq row, o>=32: Wv row), bias[o] fp32.
// ---------------------------------------------------------------------------
__global__ __launch_bounds__(256) void prep_bf16(
    const float* __restrict__ Wq, const float* __restrict__ bq,
    const float* __restrict__ Wv, const float* __restrict__ bv,
    unsigned short* __restrict__ Wb, float* __restrict__ bias)
{
    int tid = blockIdx.x * blockDim.x + threadIdx.x;
    if (tid < TOT * HID) {
        int o = tid >> 7, k = tid & 127;
        float w = (o < OUTW) ? Wq[o * HID + k] : Wv[(o - OUTW) * HID + k];
        Wb[tid] = f2bf(w);
    }
    if (tid < TOT) bias[tid] = (tid < OUTW) ? bq[tid] : bv[tid - OUTW];
}

// ---------------------------------------------------------------------------
// Proj v3 (MFMA): per wave, 16 nodes x 64 outputs via 4 N-tiles x 4 K-chunks
// of mfma_f32_16x16x32_bf16. B (weights) lives in 64 VGPRs; A converted
// fp32->bf16 on the fly. Outputs stored bf16.
// A-frag: lane l holds A[l&15][(l>>4)*8 + i]; B-frag: B[(l>>4)*8+i][l&15];
// C/D: col = l&15, row = (l>>4)*4 + j  (verified layout).
// ---------------------------------------------------------------------------
__global__ __launch_bounds__(256) void proj_mfma(
    const float* __restrict__ x,
    const unsigned short* __restrict__ Wb,
    const float* __restrict__ bias,
    unsigned short* __restrict__ P,
    unsigned short* __restrict__ Q,
    int n_nodes)
{
    const int wid  = threadIdx.x >> 6;
    const int lane = threadIdx.x & 63;
    const int lr   = lane & 15;   // A-row / B-col / C-col
    const int lg   = lane >> 4;   // k-group / C row-group
    const int m0   = blockIdx.x * 64 + wid * 16;

    // B fragments: 4 output tiles x 4 K-chunks, 16B each
    bf16x8 bfrag[4][4];
#pragma unroll
    for (int t = 0; t < 4; ++t)
#pragma unroll
        for (int kc = 0; kc < 4; ++kc)
            bfrag[t][kc] = *reinterpret_cast<const bf16x8*>(
                Wb + ((size_t)(t * 16 + lr) * HID + kc * 32 + lg * 8));

    f32x4 acc[4];
#pragma unroll
    for (int t = 0; t < 4; ++t) {
        float b = bias[t * 16 + lr];
        acc[t][0] = b; acc[t][1] = b; acc[t][2] = b; acc[t][3] = b;
    }

    const int  arow = m0 + lr;
    const bool aok  = arow < n_nodes;
    const float* ap = x + (size_t)arow * HID;

#pragma unroll
    for (int kc = 0; kc < 4; ++kc) {
        float4 f0 = make_float4(0.f, 0.f, 0.f, 0.f), f1 = f0;
        if (aok) {
            const float4* p = reinterpret_cast<const float4*>(ap + kc * 32 + lg * 8);
            f0 = p[0]; f1 = p[1];
        }
        bf16x8 a;
        a[0] = (short)f2bf(f0.x); a[1] = (short)f2bf(f0.y);
        a[2] = (short)f2bf(f0.z); a[3] = (short)f2bf(f0.w);
        a[4] = (short)f2bf(f1.x); a[5] = (short)f2bf(f1.y);
        a[6] = (short)f2bf(f1.z); a[7] = (short)f2bf(f1.w);
#pragma unroll
        for (int t = 0; t < 4; ++t)
            acc[t] = __builtin_amdgcn_mfma_f32_16x16x32_bf16(a, bfrag[t][kc], acc[t], 0, 0, 0);
    }

    const int mrow = m0 + lg * 4;
#pragma unroll
    for (int j = 0; j < 4; ++j) {
        int node = mrow + j;
        if (node < n_nodes) {
#pragma unroll
            for (int t = 0; t < 4; ++t) {
                unsigned short v = f2bf(acc[t][j]);
                if (t < 2) P[(size_t)node * OUTW + t * 16 + lr] = v;
                else       Q[(size_t)node * OUTW + (t - 2) * 16 + lr] = v;
            }
        }
    }
}

// ---------------------------------------------------------------------------
// Edge: gather bf16 P[e0], Q[e1] (64B rows), chunk-dot in fp32, sigmoid.
// ---------------------------------------------------------------------------
__global__ __launch_bounds__(256) void edge_bf16(
    const int* __restrict__ e,
    const unsigned short* __restrict__ P,
    const unsigned short* __restrict__ Q,
    const float* __restrict__ ratio_p,
    float* __restrict__ out, int E_)
{
    int i = blockIdx.x * blockDim.x + threadIdx.x;
    if (i >= E_) return;

    float scale = (1.0f - ratio_p[0]) * 0.5f;
    int e0 = e[i];
    int e1 = e[E_ + i];

    const int4v* p4 = reinterpret_cast<const int4v*>(P + (size_t)e0 * OUTW);
    const int4v* q4 = reinterpret_cast<const int4v*>(Q + (size_t)e1 * OUTW);

#pragma unroll
    for (int s = 0; s < STRU; ++s) {
        int4v a = p4[s];
        int4v b = q4[s];
        float sum = 0.f;
#pragma unroll
        for (int w = 0; w < 4; ++w) {
            float alo = __builtin_bit_cast(float, (unsigned)(a[w] << 16));
            float ahi = __builtin_bit_cast(float, (unsigned)a[w] & 0xffff0000u);
            float blo = __builtin_bit_cast(float, (unsigned)(b[w] << 16));
            float bhi = __builtin_bit_cast(float, (unsigned)b[w] & 0xffff0000u);
            sum = fmaf(alo, blo, sum);
            sum = fmaf(ahi, bhi, sum);
        }
        float sig = 1.0f / (1.0f + __expf(-sum));
        out[(size_t)s * E_ + i] = sig * scale + 1.0f;
    }
}

// ---------------------------------------------------------------------------
// Fallback: fully fused per-edge (only if workspace too small).
// ---------------------------------------------------------------------------
__global__ __launch_bounds__(256) void fused_kernel(
    const float* __restrict__ x,
    const int* __restrict__ e,
    const float* __restrict__ ratio_p,
    const float* __restrict__ Wq, const float* __restrict__ bq,
    const float* __restrict__ Wv, const float* __restrict__ bv,
    float* __restrict__ out, int E_)
{
    int i = blockIdx.x * blockDim.x + threadIdx.x;
    if (i >= E_) return;

    float scale = (1.0f - ratio_p[0]) * 0.5f;
    int e0 = e[i];
    int e1 = e[E_ + i];

    const float4* __restrict__ xu  = reinterpret_cast<const float4*>(x + (size_t)e0 * HID);
    const float4* __restrict__ xv_ = reinterpret_cast<const float4*>(x + (size_t)e1 * HID);
    const float4* __restrict__ Wq4 = reinterpret_cast<const float4*>(Wq);
    const float4* __restrict__ Wv4 = reinterpret_cast<const float4*>(Wv);

#pragma unroll 1
    for (int s = 0; s < STRU; ++s) {
        float accP[NCH], accQ[NCH];
#pragma unroll
        for (int c = 0; c < NCH; ++c) { accP[c] = bq[s*NCH+c]; accQ[c] = bv[s*NCH+c]; }
        for (int kc = 0; kc < HID / 4; ++kc) {
            float4 u = xu[kc];
            float4 v = xv_[kc];
#pragma unroll
            for (int c = 0; c < NCH; ++c) {
                int o = s * NCH + c;
                accP[c] += dot4(u, Wq4[o * (HID / 4) + kc]);
                accQ[c] += dot4(v, Wv4[o * (HID / 4) + kc]);
            }
        }
        float sum = 0.0f;
#pragma unroll
        for (int c = 0; c < NCH; ++c) sum += accP[c] * accQ[c];
        float sig = 1.0f / (1.0f + __expf(-sum));
        out[(size_t)s * E_ + i] = sig * scale + 1.0f;
    }
}

extern "C" void kernel_launch(void* const* d_in, const int* in_sizes, int n_in,
                              void* d_out, int out_size, void* d_ws, size_t ws_size,
                              hipStream_t stream)
{
    const float* x     = (const float*)d_in[0];
    const int*   e     = (const int*)  d_in[1];
    const float* ratio = (const float*)d_in[2];
    const float* Wq    = (const float*)d_in[3];
    const float* bq    = (const float*)d_in[4];
    const float* Wv    = (const float*)d_in[5];
    const float* bv    = (const float*)d_in[6];
    float* out = (float*)d_out;

    int N_ = in_sizes[0] / HID;
    int E_ = in_sizes[1] / 2;

    // workspace layout: P (bf16 N_*32) | Q (bf16 N_*32) | Wb (bf16 64*128) | bias (f32 64)
    size_t need = (size_t)N_ * OUTW * 2 * sizeof(unsigned short)
                + (size_t)TOT * HID * sizeof(unsigned short)
                + TOT * sizeof(float);
    if (ws_size >= need) {
        unsigned short* P    = (unsigned short*)d_ws;
        unsigned short* Qb   = P + (size_t)N_ * OUTW;
        unsigned short* Wb   = Qb + (size_t)N_ * OUTW;
        float*          bias = (float*)(Wb + (size_t)TOT * HID);

        prep_bf16<<<(TOT * HID + 255) / 256, 256, 0, stream>>>(Wq, bq, Wv, bv, Wb, bias);
        proj_mfma<<<(N_ + 63) / 64, 256, 0, stream>>>(x, Wb, bias, P, Qb, N_);
        edge_bf16<<<(E_ + 255) / 256, 256, 0, stream>>>(e, P, Qb, ratio, out, E_);
    } else {
        fused_kernel<<<(E_ + 255) / 256, 256, 0, stream>>>(x, e, ratio, Wq, bq, Wv, bv, out, E_);
    }
}